// Round 8
// baseline (684.858 us; speedup 1.0000x reference)
//
#include <hip/hip_runtime.h>

// Viterbi CRF decode: potentials [B,T,C] f32, transitions [C,C] f32 -> one-hot [B,T,C] f32
// B=256, T=1024, C=128.
//
// crf_fwd : max-only DP. Stashes q_t = max_p(alpha_{t-1}[p]+T[p][c]) (PRE-pot max)
//           into d_out as scratch (row 0 = zeros); LDS double-buffer carries
//           alpha_t = q_t + pot_t.
//           r8 KEY fix: 1024 threads -> per-thread trans slice is 16 floats
//           (8 f32x2), the size r2 proved the allocator keeps resident
//           (r4-r7's 32-float slices were silently spilled & reloaded every
//           step: VGPR_Count 36-48 < 32 live floats, +80 inst/step tax).
//           Lane (w 0..15, r=l>>4, i=l&15): c-pair h=w*4+r (c=2h,2h+1),
//           p-chunk i (p=8i..8i+7). pk math + select-free DPP row reduce.
// crf_bwd : per step t: M = q_t[tag] (exact, readlane) -> backpointer = first p
//           with (q_{t-1}[p]+pot_{t-1}[p]) + T[p][tag] == M (bit-exact replay
//           of fwd's adds) -> ballot+ffs. No max-reduce in the serial chain.

typedef float f32x2 __attribute__((ext_vector_type(2)));

constexpr int NB = 256;
constexpr int NT = 1024;
constexpr int NC = 128;

template <int CTRL>
__device__ __forceinline__ float fmax_dpp(float v) {
  int x = __builtin_amdgcn_update_dpp(__float_as_int(v), __float_as_int(v),
                                      CTRL, 0xF, 0xF, false);
  return fmaxf(v, __int_as_float(x));
}
__device__ __forceinline__ f32x2 pkmax(f32x2 a, f32x2 b) {
  return __builtin_elementwise_max(a, b);
}
__device__ __forceinline__ float wave_max_to_lane63(float m) {
  m = fmax_dpp<0x111>(m);  // row_shr:1
  m = fmax_dpp<0x112>(m);  // row_shr:2
  m = fmax_dpp<0x114>(m);  // row_shr:4
  m = fmax_dpp<0x118>(m);  // row_shr:8
  m = fmax_dpp<0x142>(m);  // row_bcast:15
  m = fmax_dpp<0x143>(m);  // row_bcast:31 -> lane63 has full max
  return m;
}

// ---------------- forward ----------------
// alpha LDS layout: p at float index 12*(p>>3) + (p&7); chunk i = floats 12i..12i+7.

constexpr int ABUF = 192;

#define MKT(T, EA, EB)                                        \
  f32x2 T;                                                    \
  {                                                           \
    float _x = (EA), _y = (EB);                               \
    asm volatile("" : "+v"(_x), "+v"(_y));                    \
    T = f32x2{_x, _y};                                        \
  }

// One DP step. QJ/PCJ are named writer-lane registers; CUR compile-time.
#define STEP(QJ, PCJ, CUR)                                                  \
  do {                                                                      \
    const float4* _af = (CUR) ? afB : afA;                                  \
    float4 _x0 = _af[0];                                                    \
    float4 _x1 = _af[1];                                                    \
    f32x2 _a0 = f32x2{_x0.x, _x0.y};                                        \
    f32x2 _a1 = f32x2{_x0.z, _x0.w};                                        \
    f32x2 _a2 = f32x2{_x1.x, _x1.y};                                        \
    f32x2 _a3 = f32x2{_x1.z, _x1.w};                                        \
    f32x2 _s = pkmax(pkmax(_a0 + TA0, _a1 + TA1),                           \
                     pkmax(_a2 + TA2, _a3 + TA3));                          \
    float _m0 = fmaxf(_s.x, _s.y);                                          \
    _s = pkmax(pkmax(_a0 + TB0, _a1 + TB1),                                 \
               pkmax(_a2 + TB2, _a3 + TB3));                                \
    float _m1 = fmaxf(_s.x, _s.y);                                          \
    /* select-free 16-lane reduce: xor1, xor2, ror4, ror8 -> all lanes */   \
    _m0 = fmax_dpp<0xB1>(_m0);   _m1 = fmax_dpp<0xB1>(_m1);                 \
    _m0 = fmax_dpp<0x4E>(_m0);   _m1 = fmax_dpp<0x4E>(_m1);                 \
    _m0 = fmax_dpp<0x124>(_m0);  _m1 = fmax_dpp<0x124>(_m1);                \
    _m0 = fmax_dpp<0x128>(_m0);  _m1 = fmax_dpp<0x128>(_m1);                \
    if (wr) {                                                               \
      float _q = (i & 1) ? _m1 : _m0;                                       \
      alpha[((CUR) ^ 1) * ABUF + widx] = _q + (PCJ);                        \
      (QJ) = _q;                                                            \
    }                                                                       \
    asm volatile("s_waitcnt lgkmcnt(0)\n\ts_barrier" ::: "memory");         \
  } while (0)

__global__ __launch_bounds__(1024, 4)
void crf_fwd(const float* __restrict__ pot, const float* __restrict__ trans,
             float* __restrict__ out) {
  __shared__ __align__(16) float alpha[2 * ABUF];

  const int tid = threadIdx.x;
  const int b = blockIdx.x;
  const int w = tid >> 6;          // wave 0..15
  const int l = tid & 63;          // lane
  const int r = l >> 4;            // 16-lane row 0..3
  const int i = l & 15;            // p-chunk (p = 8i..8i+7)
  const int h = w * 4 + r;         // c-pair 0..63 (c0 = 2h, c1 = 2h+1)
  const bool wr = (i >= 14);       // writer lanes: i=14 -> c0, i=15 -> c1
  const int cw = 2 * h + (i & 1);  // writer's c
  const int widx = 12 * (cw >> 3) + (cw & 7);

  const float* potb = pot + (size_t)b * NT * NC;
  float* outb = out + (size_t)b * NT * NC;

  // trans slice: 8 rows (p=8i+k), c-pair columns -> repack to p-pairs per c.
  const float* tb = trans + (8 * i) * NC + 2 * h;
  f32x2 R0 = *(const f32x2*)(tb + 0 * NC);
  f32x2 R1 = *(const f32x2*)(tb + 1 * NC);
  f32x2 R2 = *(const f32x2*)(tb + 2 * NC);
  f32x2 R3 = *(const f32x2*)(tb + 3 * NC);
  f32x2 R4 = *(const f32x2*)(tb + 4 * NC);
  f32x2 R5 = *(const f32x2*)(tb + 5 * NC);
  f32x2 R6 = *(const f32x2*)(tb + 6 * NC);
  f32x2 R7 = *(const f32x2*)(tb + 7 * NC);
  MKT(TA0, R0.x, R1.x) MKT(TA1, R2.x, R3.x) MKT(TA2, R4.x, R5.x) MKT(TA3, R6.x, R7.x)
  MKT(TB0, R0.y, R1.y) MKT(TB1, R2.y, R3.y) MKT(TB2, R4.y, R5.y) MKT(TB3, R6.y, R7.y)

  float pc0, pc1, pc2, pc3;   // pot prefetch (writer lanes)
  float q0, q1, q2, q3;       // q accumulators (writer lanes)
  if (wr) {
    alpha[widx] = potb[cw];   // alpha_0 = pot[:,0,:]
    outb[cw] = 0.0f;          // q_0 := 0
    pc0 = potb[1 * NC + cw]; pc1 = potb[2 * NC + cw];
    pc2 = potb[3 * NC + cw]; pc3 = potb[4 * NC + cw];
  }
  asm volatile("s_waitcnt lgkmcnt(0)\n\ts_barrier" ::: "memory");

  const float4* afA = (const float4*)(alpha) + 3 * i;
  const float4* afB = (const float4*)(alpha + ABUF) + 3 * i;

  // 255 groups of 4 steps: t = 1..1020 (CUR starts 0 each group)
  for (int g = 0; g < 255; ++g) {
    STEP(q0, pc0, 0); STEP(q1, pc1, 1); STEP(q2, pc2, 0); STEP(q3, pc3, 1);
    if (wr) {
      float* fo = outb + (size_t)(1 + 4 * g) * NC + cw;     // flush q rows
      fo[0] = q0; fo[NC] = q1; fo[2 * NC] = q2; fo[3 * NC] = q3;
      int nr = 5 + 4 * g;                                    // prefetch rows
      const float* pp = potb + (size_t)nr * NC + cw;
      pc0 = pp[0];
      pc1 = pp[NC];
      pc2 = pp[2 * NC];
      pc3 = (nr + 3 > NT - 1) ? pp[2 * NC] : pp[3 * NC];     // clamp g=254
    }
  }
  // tail: t = 1021..1023
  STEP(q0, pc0, 0); STEP(q1, pc1, 1); STEP(q2, pc2, 0);
  if (wr) {
    float* fo = outb + (size_t)1021 * NC + cw;
    fo[0] = q0; fo[NC] = q1; fo[2 * NC] = q2;
  }
}

// ---------------- backward ----------------
// tTp[c][l] = (T[l][c], T[64+l][c]) as float2 in LDS (64 KiB).
// Wave 0 chases; per step only an equality scan against M = q_t[tag].

__global__ __launch_bounds__(256)
void crf_bwd(const float* __restrict__ pot, const float* __restrict__ trans,
             float* __restrict__ out) {
  extern __shared__ float tTf[];   // float2[NC][64] interleaved
  const int tid = threadIdx.x;
  const int b = blockIdx.x;
  const float* potb = pot + (size_t)b * NT * NC;
  float* outb = out + (size_t)b * NT * NC;

  {
    const int rr = tid >> 1;   // source row p of trans
    const int h = tid & 1;     // which half of the row
    const float4* src = (const float4*)(trans + rr * NC + h * 64);
    const int lo = rr & 63, hb = rr >> 6;
    #pragma unroll
    for (int j = 0; j < 16; ++j) {
      float4 q = src[j];
      int cb = h * 64 + 4 * j;
      tTf[(cb + 0) * 128 + lo * 2 + hb] = q.x;
      tTf[(cb + 1) * 128 + lo * 2 + hb] = q.y;
      tTf[(cb + 2) * 128 + lo * 2 + hb] = q.z;
      tTf[(cb + 3) * 128 + lo * 2 + hb] = q.w;
    }
  }
  __syncthreads();
  if (tid >= 64) return;
  const int l = tid;
  const f32x2* tTp = (const f32x2*)tTf;

  // init at t = NT-1: alpha_last = q_last + pot_last; full argmax once
  float qlo_t = outb[(NT - 1) * NC + l];
  float qhi_t = outb[(NT - 1) * NC + 64 + l];
  float alo_t = qlo_t + potb[(NT - 1) * NC + l];
  float ahi_t = qhi_t + potb[(NT - 1) * NC + 64 + l];
  float m0 = wave_max_to_lane63(fmaxf(alo_t, ahi_t));
  float M0 = __int_as_float(__builtin_amdgcn_readlane(__float_as_int(m0), 63));
  unsigned long long bl = __ballot(alo_t == M0);
  unsigned long long bh = __ballot(ahi_t == M0);
  int tag = bl ? (__ffsll((long long)bl) - 1)
               : (64 + __ffsll((long long)bh) - 1);

  // prefetch rows 1022..1015 (q and pot), precompute alpha
  float cqlo[8], cqhi[8], calo[8], cahi[8];
  float nqlo[8], nqhi[8], nplo[8], nphi[8];
  #pragma unroll
  for (int j = 0; j < 8; ++j) {
    int rw = NT - 2 - j;
    cqlo[j] = outb[rw * NC + l];
    cqhi[j] = outb[rw * NC + 64 + l];
    calo[j] = cqlo[j] + potb[rw * NC + l];
    cahi[j] = cqhi[j] + potb[rw * NC + 64 + l];
  }

  for (int g = 0; g < 128; ++g) {
    #pragma unroll
    for (int j = 0; j < 8; ++j) {      // prefetch group g+1
      int rw = NT - 10 - 8 * g - j;
      if (rw < 0) rw = 0;
      nqlo[j] = outb[rw * NC + l];
      nqhi[j] = outb[rw * NC + 64 + l];
      nplo[j] = potb[rw * NC + l];
      nphi[j] = potb[rw * NC + 64 + l];
    }
    #pragma unroll
    for (int j = 0; j < 8; ++j) {
      int t = NT - 1 - 8 * g - j;
      if (t >= 1) {
        outb[t * NC + l]      = (l == tag) ? 1.0f : 0.0f;
        outb[t * NC + 64 + l] = (64 + l == tag) ? 1.0f : 0.0f;
        int Mlo = __builtin_amdgcn_readlane(__float_as_int(qlo_t), tag & 63);
        int Mhi = __builtin_amdgcn_readlane(__float_as_int(qhi_t), tag & 63);
        float M = __int_as_float((tag < 64) ? Mlo : Mhi);
        f32x2 tt = tTp[tag * 64 + l];
        float vlo = calo[j] + tt.x;
        float vhi = cahi[j] + tt.y;
        unsigned long long el = __ballot(vlo == M);
        unsigned long long eh = __ballot(vhi == M);
        tag = el ? (__ffsll((long long)el) - 1)
                 : (64 + __ffsll((long long)eh) - 1);
        qlo_t = cqlo[j];
        qhi_t = cqhi[j];
      }
    }
    #pragma unroll
    for (int j = 0; j < 8; ++j) {
      cqlo[j] = nqlo[j]; cqhi[j] = nqhi[j];
      calo[j] = nqlo[j] + nplo[j];
      cahi[j] = nqhi[j] + nphi[j];
    }
  }
  outb[l]      = (l == tag) ? 1.0f : 0.0f;
  outb[64 + l] = (64 + l == tag) ? 1.0f : 0.0f;
}

// ---------------- launch ----------------

extern "C" void kernel_launch(void* const* d_in, const int* in_sizes, int n_in,
                              void* d_out, int out_size, void* d_ws, size_t ws_size,
                              hipStream_t stream) {
  const float* pot   = (const float*)d_in[0];
  const float* trans = (const float*)d_in[1];
  float* out = (float*)d_out;

  hipFuncSetAttribute((const void*)crf_bwd,
                      hipFuncAttributeMaxDynamicSharedMemorySize, NC * NC * 4);

  crf_fwd<<<NB, 1024, 0, stream>>>(pot, trans, out);
  crf_bwd<<<NB, 256, NC * NC * 4, stream>>>(pot, trans, out);
}

// Round 9
// 436.259 us; speedup vs baseline: 1.5698x; 1.5698x over previous
//
#include <hip/hip_runtime.h>

// Viterbi CRF decode: potentials [B,T,C] f32, transitions [C,C] f32 -> one-hot [B,T,C] f32
// B=256, T=1024, C=128.
//
// crf_fwd : max-only DP, inner loop ENTIRELY in inline asm (r9).
//           r4-r8 post-mortems: the register allocator refuses to keep the
//           loop-invariant transition slice resident at HIP level (VGPR_Count
//           24-48 vs 32 live floats needed) and re-loads it every step
//           (~2-3x architected instruction count). In asm, trans sits in 32
//           operand VGPRs that cannot be spilled; temps are clobbers v44-v63.
//           Per step: 2 ds_read_b128, 4x(4 pk_add + 3 max3 + 1 max) trees,
//           16 fused DPP maxes (xor1,xor2,ror4,ror8 - r7-validated, value
//           bit-exact), 3 cndmask, exec-masked {alpha->LDS, q->global},
//           lgkmcnt(0)+barrier. Pot prefetch depth-4 via SRD buffer_load
//           (OOB-safe), vmcnt(4) once per 4-step body.
// crf_bwd : unchanged (r4-validated): M = q_t[tag] via readlane; backpointer =
//           first p with (q+pot)+T == M (bit-exact replay) via ballot+ffs.

typedef float f32x2 __attribute__((ext_vector_type(2)));
typedef unsigned int u32x4 __attribute__((ext_vector_type(4)));

constexpr int NB = 256;
constexpr int NT = 1024;
constexpr int NC = 128;

template <int CTRL>
__device__ __forceinline__ float fmax_dpp(float v) {
  int x = __builtin_amdgcn_update_dpp(__float_as_int(v), __float_as_int(v),
                                      CTRL, 0xF, 0xF, false);
  return fmaxf(v, __int_as_float(x));
}
__device__ __forceinline__ float wave_max_to_lane63(float m) {
  m = fmax_dpp<0x111>(m);  // row_shr:1
  m = fmax_dpp<0x112>(m);  // row_shr:2
  m = fmax_dpp<0x114>(m);  // row_shr:4
  m = fmax_dpp<0x118>(m);  // row_shr:8
  m = fmax_dpp<0x142>(m);  // row_bcast:15
  m = fmax_dpp<0x143>(m);  // row_bcast:31 -> lane63 has full max
  return m;
}

// ---------------- forward ----------------
// alpha LDS: p at float index 12*(p>>3)+(p&7); chunk i = floats 12i..12i+7.
constexpr int ABUF = 192;

// one c's 8-wide max tree: 4 pk_add + 3 max3 + 1 max -> MD (exact-assoc max)
#define T_C(T0, T1, T2, T3, MD)                              \
  "v_pk_add_f32 v[52:53], v[60:61], %[" T0 "]\n\t"           \
  "v_pk_add_f32 v[54:55], v[62:63], %[" T1 "]\n\t"           \
  "v_pk_add_f32 v[46:47], v[56:57], %[" T2 "]\n\t"           \
  "v_pk_add_f32 v[44:45], v[58:59], %[" T3 "]\n\t"           \
  "v_max3_f32 v52, v52, v53, v54\n\t"                        \
  "v_max3_f32 v55, v55, v46, v47\n\t"                        \
  "v_max3_f32 v52, v52, v55, v44\n\t"                        \
  "v_max_f32 " MD ", v52, v45\n\t"

#define DPP4(CTL)                                                          \
  "v_max_f32_dpp v48, v48, v48 " CTL " row_mask:0xf bank_mask:0xf\n\t"     \
  "v_max_f32_dpp v49, v49, v49 " CTL " row_mask:0xf bank_mask:0xf\n\t"     \
  "v_max_f32_dpp v50, v50, v50 " CTL " row_mask:0xf bank_mask:0xf\n\t"     \
  "v_max_f32_dpp v51, v51, v51 " CTL " row_mask:0xf bank_mask:0xf\n\t"

// one DP step: read buf RD, write buf WR, pot reg PC, q-store byte offset SOFF
#define STEP_S(RD, WR, PC, SOFF)                                           \
  "ds_read_b128 v[60:63], %[" RD "]\n\t"                                   \
  "ds_read_b128 v[56:59], %[" RD "] offset:16\n\t"                         \
  "s_waitcnt lgkmcnt(0)\n\t"                                               \
  T_C("t00", "t01", "t02", "t03", "v48")                                   \
  T_C("t10", "t11", "t12", "t13", "v49")                                   \
  T_C("t20", "t21", "t22", "t23", "v50")                                   \
  T_C("t30", "t31", "t32", "t33", "v51")                                   \
  DPP4("quad_perm:[1,0,3,2]")                                              \
  DPP4("quad_perm:[2,3,0,1]")                                              \
  DPP4("row_ror:4")                                                        \
  DPP4("row_ror:8")                                                        \
  "v_cndmask_b32 v46, v48, v49, %[sel1]\n\t"                               \
  "v_cndmask_b32 v47, v50, v51, %[sel1]\n\t"                               \
  "v_cndmask_b32 v47, v46, v47, %[sel2]\n\t"                               \
  "s_mov_b64 exec, %[wmask]\n\t"                                           \
  "v_add_f32 v46, v47, %[" PC "]\n\t"                                      \
  "ds_write_b32 %[" WR "], v46\n\t"                                        \
  "global_store_dword %[qoff], v47, %[sout] offset:" SOFF "\n\t"           \
  "s_mov_b64 exec, -1\n\t"                                                 \
  "s_waitcnt lgkmcnt(0)\n\t"                                               \
  "s_barrier\n\t"

__global__ __launch_bounds__(512, 2)
void crf_fwd(const float* __restrict__ pot, const float* __restrict__ trans,
             float* __restrict__ out) {
  __shared__ __align__(16) float alpha[2 * ABUF];

  const int tid = threadIdx.x;
  const int b = blockIdx.x;
  const int w = tid >> 6;          // wave 0..7
  const int l = tid & 63;          // lane
  const int r = l >> 4;            // 16-lane row 0..3
  const int i = l & 15;            // p-chunk (p = 8i..8i+7)
  const int g = w * 4 + r;         // c-quad 0..31
  const bool wr = (i >= 12);       // writer lanes (i=12..15 -> c0..c3)
  const int cw = 4 * g + (i & 3);  // writer's c
  const int widx = 12 * (cw >> 3) + (cw & 7);

  const float* potb = pot + (size_t)b * NT * NC;
  float* outb = out + (size_t)b * NT * NC;

  // transitions -> 16 f32x2 asm operands: t<c><k> = (T[8i+2k][4g+c], T[8i+2k+1][4g+c])
  const float* tb = trans + (8 * i) * NC + 4 * g;
  float4 L0 = *(const float4*)(tb + 0 * NC);
  float4 L1 = *(const float4*)(tb + 1 * NC);
  float4 L2 = *(const float4*)(tb + 2 * NC);
  float4 L3 = *(const float4*)(tb + 3 * NC);
  float4 L4 = *(const float4*)(tb + 4 * NC);
  float4 L5 = *(const float4*)(tb + 5 * NC);
  float4 L6 = *(const float4*)(tb + 6 * NC);
  float4 L7 = *(const float4*)(tb + 7 * NC);
  f32x2 t00 = {L0.x, L1.x}, t01 = {L2.x, L3.x}, t02 = {L4.x, L5.x}, t03 = {L6.x, L7.x};
  f32x2 t10 = {L0.y, L1.y}, t11 = {L2.y, L3.y}, t12 = {L4.y, L5.y}, t13 = {L6.y, L7.y};
  f32x2 t20 = {L0.z, L1.z}, t21 = {L2.z, L3.z}, t22 = {L4.z, L5.z}, t23 = {L6.z, L7.z};
  f32x2 t30 = {L0.w, L1.w}, t31 = {L2.w, L3.w}, t32 = {L4.w, L5.w}, t33 = {L6.w, L7.w};

  // LDS byte addresses (addrspace apertures are 2^32-aligned -> low 32 bits = LDS offset)
  unsigned rda = (unsigned)(size_t)(alpha + 12 * i);
  unsigned rdb = (unsigned)(size_t)(alpha + ABUF + 12 * i);
  unsigned wra = (unsigned)(size_t)(alpha + widx);
  unsigned wrb = (unsigned)(size_t)(alpha + ABUF + widx);

  unsigned qoff = (unsigned)((1 * NC + cw) * 4);                       // q row 1
  unsigned poff = ((unsigned)b * (NT * NC) + 5 * NC + cw) * 4u;        // pot row 5
  unsigned long long sout = (unsigned long long)(size_t)outb;
  unsigned long long pbase = (unsigned long long)(size_t)pot;
  u32x4 srd;
  srd.x = (unsigned)pbase;
  srd.y = (unsigned)(pbase >> 32) & 0xFFFFu;   // stride 0
  srd.z = (unsigned)(NB * NT * NC) * 4u;       // num_records (bytes): OOB load -> 0
  srd.w = 0x00020000u;
  unsigned long long sel1 = 0xAAAAAAAAAAAAAAAAull;   // lanes with (i&1)
  unsigned long long sel2 = 0xCCCCCCCCCCCCCCCCull;   // lanes with (i&2)
  unsigned long long wmask = 0xF000F000F000F000ull;  // lanes with (i>=12)
  int cnt = 254;

  float pc0 = potb[1 * NC + cw], pc1 = potb[2 * NC + cw];
  float pc2 = potb[3 * NC + cw], pc3 = potb[4 * NC + cw];
  float pn0 = 0.f, pn1 = 0.f, pn2 = 0.f, pn3 = 0.f;

  if (wr) {
    alpha[widx] = potb[cw];   // alpha_0 = pot[:,0,:]
    outb[cw] = 0.0f;          // q_0 := 0  (alpha_0 = 0 + pot_0)
  }
  __syncthreads();

  asm volatile(
      // prologue prefetch: pot rows 5..8 -> pn
      "buffer_load_dword %[pn0], %[poff], %[srd], 0 offen\n\t"
      "buffer_load_dword %[pn1], %[poff], %[srd], 0 offen offset:512\n\t"
      "buffer_load_dword %[pn2], %[poff], %[srd], 0 offen offset:1024\n\t"
      "buffer_load_dword %[pn3], %[poff], %[srd], 0 offen offset:1536\n\t"
      "L_crfmain_%=:\n\t"
      // 4 steps: t0 .. t0+3
      STEP_S("rda", "wrb", "pc0", "0")
      STEP_S("rdb", "wra", "pc1", "512")
      STEP_S("rda", "wrb", "pc2", "1024")
      STEP_S("rdb", "wra", "pc3", "1536")
      // body end: rotate prefetch (vmcnt(4): 4 stores may linger, loads done)
      "s_waitcnt vmcnt(4)\n\t"
      "v_mov_b32 %[pc0], %[pn0]\n\t"
      "v_mov_b32 %[pc1], %[pn1]\n\t"
      "v_mov_b32 %[pc2], %[pn2]\n\t"
      "v_mov_b32 %[pc3], %[pn3]\n\t"
      "v_add_u32 %[poff], 0x800, %[poff]\n\t"
      "v_add_u32 %[qoff], 0x800, %[qoff]\n\t"
      "buffer_load_dword %[pn0], %[poff], %[srd], 0 offen\n\t"
      "buffer_load_dword %[pn1], %[poff], %[srd], 0 offen offset:512\n\t"
      "buffer_load_dword %[pn2], %[poff], %[srd], 0 offen offset:1024\n\t"
      "buffer_load_dword %[pn3], %[poff], %[srd], 0 offen offset:1536\n\t"
      "s_sub_u32 %[cnt], %[cnt], 1\n\t"
      "s_cmp_lg_u32 %[cnt], 0\n\t"
      "s_cbranch_scc1 L_crfmain_%=\n\t"
      // E: t = 1017..1020 (uses pc rotated at loop's last body end)
      STEP_S("rda", "wrb", "pc0", "0")
      STEP_S("rdb", "wra", "pc1", "512")
      STEP_S("rda", "wrb", "pc2", "1024")
      STEP_S("rdb", "wra", "pc3", "1536")
      "s_waitcnt vmcnt(4)\n\t"
      "v_mov_b32 %[pc0], %[pn0]\n\t"
      "v_mov_b32 %[pc1], %[pn1]\n\t"
      "v_mov_b32 %[pc2], %[pn2]\n\t"
      "v_add_u32 %[qoff], 0x800, %[qoff]\n\t"
      // T: t = 1021..1023
      STEP_S("rda", "wrb", "pc0", "0")
      STEP_S("rdb", "wra", "pc1", "512")
      STEP_S("rda", "wrb", "pc2", "1024")
      : [pc0] "+v"(pc0), [pc1] "+v"(pc1), [pc2] "+v"(pc2), [pc3] "+v"(pc3),
        [pn0] "+v"(pn0), [pn1] "+v"(pn1), [pn2] "+v"(pn2), [pn3] "+v"(pn3),
        [qoff] "+v"(qoff), [poff] "+v"(poff), [cnt] "+s"(cnt)
      : [t00] "v"(t00), [t01] "v"(t01), [t02] "v"(t02), [t03] "v"(t03),
        [t10] "v"(t10), [t11] "v"(t11), [t12] "v"(t12), [t13] "v"(t13),
        [t20] "v"(t20), [t21] "v"(t21), [t22] "v"(t22), [t23] "v"(t23),
        [t30] "v"(t30), [t31] "v"(t31), [t32] "v"(t32), [t33] "v"(t33),
        [rda] "v"(rda), [rdb] "v"(rdb), [wra] "v"(wra), [wrb] "v"(wrb),
        [sout] "s"(sout), [srd] "s"(srd),
        [sel1] "s"(sel1), [sel2] "s"(sel2), [wmask] "s"(wmask)
      : "memory", "scc",
        "v44", "v45", "v46", "v47", "v48", "v49", "v50", "v51",
        "v52", "v53", "v54", "v55", "v56", "v57", "v58", "v59",
        "v60", "v61", "v62", "v63");
}

// ---------------- backward ----------------
// tTp[c][l] = (T[l][c], T[64+l][c]) as float2 in LDS (64 KiB).
// Wave 0 chases; per step only an equality scan against M = q_t[tag].

__global__ __launch_bounds__(256)
void crf_bwd(const float* __restrict__ pot, const float* __restrict__ trans,
             float* __restrict__ out) {
  extern __shared__ float tTf[];   // float2[NC][64] interleaved
  const int tid = threadIdx.x;
  const int b = blockIdx.x;
  const float* potb = pot + (size_t)b * NT * NC;
  float* outb = out + (size_t)b * NT * NC;

  {
    const int rr = tid >> 1;   // source row p of trans
    const int h = tid & 1;     // which half of the row
    const float4* src = (const float4*)(trans + rr * NC + h * 64);
    const int lo = rr & 63, hb = rr >> 6;
    #pragma unroll
    for (int j = 0; j < 16; ++j) {
      float4 q = src[j];
      int cb = h * 64 + 4 * j;
      tTf[(cb + 0) * 128 + lo * 2 + hb] = q.x;
      tTf[(cb + 1) * 128 + lo * 2 + hb] = q.y;
      tTf[(cb + 2) * 128 + lo * 2 + hb] = q.z;
      tTf[(cb + 3) * 128 + lo * 2 + hb] = q.w;
    }
  }
  __syncthreads();
  if (tid >= 64) return;
  const int l = tid;
  const f32x2* tTp = (const f32x2*)tTf;

  // init at t = NT-1: alpha_last = q_last + pot_last; full argmax once
  float qlo_t = outb[(NT - 1) * NC + l];
  float qhi_t = outb[(NT - 1) * NC + 64 + l];
  float alo_t = qlo_t + potb[(NT - 1) * NC + l];
  float ahi_t = qhi_t + potb[(NT - 1) * NC + 64 + l];
  float m0 = wave_max_to_lane63(fmaxf(alo_t, ahi_t));
  float M0 = __int_as_float(__builtin_amdgcn_readlane(__float_as_int(m0), 63));
  unsigned long long bl = __ballot(alo_t == M0);
  unsigned long long bh = __ballot(ahi_t == M0);
  int tag = bl ? (__ffsll((long long)bl) - 1)
               : (64 + __ffsll((long long)bh) - 1);

  // prefetch rows 1022..1015 (q and pot), precompute alpha
  float cqlo[8], cqhi[8], calo[8], cahi[8];
  float nqlo[8], nqhi[8], nplo[8], nphi[8];
  #pragma unroll
  for (int j = 0; j < 8; ++j) {
    int rw = NT - 2 - j;
    cqlo[j] = outb[rw * NC + l];
    cqhi[j] = outb[rw * NC + 64 + l];
    calo[j] = cqlo[j] + potb[rw * NC + l];
    cahi[j] = cqhi[j] + potb[rw * NC + 64 + l];
  }

  for (int g = 0; g < 128; ++g) {
    #pragma unroll
    for (int j = 0; j < 8; ++j) {      // prefetch group g+1
      int rw = NT - 10 - 8 * g - j;
      if (rw < 0) rw = 0;
      nqlo[j] = outb[rw * NC + l];
      nqhi[j] = outb[rw * NC + 64 + l];
      nplo[j] = potb[rw * NC + l];
      nphi[j] = potb[rw * NC + 64 + l];
    }
    #pragma unroll
    for (int j = 0; j < 8; ++j) {
      int t = NT - 1 - 8 * g - j;
      if (t >= 1) {
        outb[t * NC + l]      = (l == tag) ? 1.0f : 0.0f;
        outb[t * NC + 64 + l] = (64 + l == tag) ? 1.0f : 0.0f;
        int Mlo = __builtin_amdgcn_readlane(__float_as_int(qlo_t), tag & 63);
        int Mhi = __builtin_amdgcn_readlane(__float_as_int(qhi_t), tag & 63);
        float M = __int_as_float((tag < 64) ? Mlo : Mhi);
        f32x2 tt = tTp[tag * 64 + l];
        float vlo = calo[j] + tt.x;
        float vhi = cahi[j] + tt.y;
        unsigned long long el = __ballot(vlo == M);
        unsigned long long eh = __ballot(vhi == M);
        tag = el ? (__ffsll((long long)el) - 1)
                 : (64 + __ffsll((long long)eh) - 1);
        qlo_t = cqlo[j];
        qhi_t = cqhi[j];
      }
    }
    #pragma unroll
    for (int j = 0; j < 8; ++j) {
      cqlo[j] = nqlo[j]; cqhi[j] = nqhi[j];
      calo[j] = nqlo[j] + nplo[j];
      cahi[j] = nqhi[j] + nphi[j];
    }
  }
  outb[l]      = (l == tag) ? 1.0f : 0.0f;
  outb[64 + l] = (64 + l == tag) ? 1.0f : 0.0f;
}

// ---------------- launch ----------------

extern "C" void kernel_launch(void* const* d_in, const int* in_sizes, int n_in,
                              void* d_out, int out_size, void* d_ws, size_t ws_size,
                              hipStream_t stream) {
  const float* pot   = (const float*)d_in[0];
  const float* trans = (const float*)d_in[1];
  float* out = (float*)d_out;

  hipFuncSetAttribute((const void*)crf_bwd,
                      hipFuncAttributeMaxDynamicSharedMemorySize, NC * NC * 4);

  crf_fwd<<<NB, 512, 0, stream>>>(pot, trans, out);
  crf_bwd<<<NB, 256, NC * NC * 4, stream>>>(pot, trans, out);
}